// Round 3
// baseline (107.999 us; speedup 1.0000x reference)
//
#include <hip/hip_runtime.h>

#define HDIM 768
#define EDIM 128
#define BDIM 64

#define NCORE_BLOCKS 256   // 2 blocks per slab i; 8 float4 per thread
#define NPROJ_BLOCKS 768   // 3072 waves: 3 matrices x 64 b x 16 i-chunks
#define NGRID (NCORE_BLOCKS + NPROJ_BLOCKS)

// ws layout (floats): [0] counter (u32, memset to 0 pre-launch)
//                     [64..320)   partials[256]  (halfsums, 2 per slab i)
//                     [1024..25600) P[3][64][128]
#define WS_PARTIALS 64
#define WS_P 1024

__global__ __launch_bounds__(256) void tucker_kernel(
    const float* __restrict__ core,
    const float* __restrict__ head_src, const float* __restrict__ rel_src,
    const float* __restrict__ tail_src,
    const float* __restrict__ W_e, const float* __restrict__ b_e,
    const float* __restrict__ W_r, const float* __restrict__ b_r,
    float* __restrict__ ws, float* __restrict__ out) {
    float* partials = ws + WS_PARTIALS;
    float* P        = ws + WS_P;
    unsigned* cnt   = (unsigned*)ws;

    const int blk = blockIdx.x;
    const int t = threadIdx.x;
    const int wave = t >> 6, lane = t & 63;

    __shared__ float wpart[4];
    __shared__ int is_last;

    if (blk < NCORE_BLOCKS) {
        // core slab half-sum: slab i = blk>>1, half = blk&1 (8192 floats)
        const int i = blk >> 1, h = blk & 1;
        const float4* p = (const float4*)(core + (size_t)i * 16384 + (size_t)h * 8192);
        float4 v0 = p[t], v1 = p[t + 256], v2 = p[t + 512], v3 = p[t + 768];
        float4 v4 = p[t + 1024], v5 = p[t + 1280], v6 = p[t + 1536], v7 = p[t + 1792];
        float s = ((v0.x + v0.y) + (v0.z + v0.w)) + ((v1.x + v1.y) + (v1.z + v1.w))
                + ((v2.x + v2.y) + (v2.z + v2.w)) + ((v3.x + v3.y) + (v3.z + v3.w))
                + ((v4.x + v4.y) + (v4.z + v4.w)) + ((v5.x + v5.y) + (v5.z + v5.w))
                + ((v6.x + v6.y) + (v6.z + v6.w)) + ((v7.x + v7.y) + (v7.z + v7.w));
        for (int off = 32; off; off >>= 1) s += __shfl_down(s, off, 64);
        if (lane == 0) wpart[wave] = s;
        __syncthreads();
        if (t == 0) partials[blk] = (wpart[0] + wpart[1]) + (wpart[2] + wpart[3]);
    } else {
        // projections: wave task = (m, b, i-chunk of 8 channels)
        const int wt  = (blk - NCORE_BLOCKS) * 4 + wave;  // 0..3071
        const int ich = wt & 15;
        const int mb  = wt >> 4;                          // 0..191
        const int m   = mb >> 6;                          // 0=head 1=rel 2=tail
        const int b   = mb & 63;

        const float* src  = (m == 0) ? head_src : (m == 1) ? rel_src : tail_src;
        const float* W    = (m == 1) ? W_r : W_e;
        const float* bias = (m == 1) ? b_r : b_e;

        const float4* s4 = (const float4*)(src + b * HDIM);
        const float4 x0 = s4[lane], x1 = s4[lane + 64], x2 = s4[lane + 128];

        const int i0 = ich * 8;
#pragma unroll
        for (int u = 0; u < 8; ++u) {
            const int i = i0 + u;
            const float4* w4 = (const float4*)(W + i * HDIM);
            const float4 w0 = w4[lane], w1 = w4[lane + 64], w2 = w4[lane + 128];
            float d = w0.x * x0.x + w0.y * x0.y + w0.z * x0.z + w0.w * x0.w
                    + w1.x * x1.x + w1.y * x1.y + w1.z * x1.z + w1.w * x1.w
                    + w2.x * x2.x + w2.y * x2.y + w2.z * x2.z + w2.w * x2.w;
            for (int off = 32; off; off >>= 1) d += __shfl_down(d, off, 64);
            if (lane == 0) P[(m * BDIM + b) * EDIM + i] = d + bias[i];
        }
        __syncthreads();  // all proj stores issued+drained before the fence
    }

    // ---- last-block-finishes: device-scope fence + counter ----
    if (t == 0) {
        __threadfence();                       // release: wb this XCD's L2
        unsigned old = atomicAdd(cnt, 1u);     // device-scope atomic
        is_last = (old == NGRID - 1);
    }
    __syncthreads();
    if (!is_last) return;
    __threadfence();                           // acquire: inv caches

    // final phase: S[i] then energy[b]
    __shared__ float s_S[EDIM];
    if (t < EDIM) s_S[t] = partials[2 * t] + partials[2 * t + 1];
    __syncthreads();

    const float* P0 = P;
    const float* P1 = P + BDIM * EDIM;
    const float* P2 = P + 2 * BDIM * EDIM;
    for (int b = wave; b < BDIM; b += 4) {
        const int i1 = lane, i2 = lane + 64;
        float v = s_S[i1] * P0[b * EDIM + i1] * P1[b * EDIM + i1] * P2[b * EDIM + i1]
                + s_S[i2] * P0[b * EDIM + i2] * P1[b * EDIM + i2] * P2[b * EDIM + i2];
        for (int off = 32; off; off >>= 1) v += __shfl_down(v, off, 64);
        if (lane == 0) out[b] = -v;
    }
}

extern "C" void kernel_launch(void* const* d_in, const int* in_sizes, int n_in,
                              void* d_out, int out_size, void* d_ws, size_t ws_size,
                              hipStream_t stream) {
    const float* head_src = (const float*)d_in[0];
    const float* rel_src  = (const float*)d_in[1];
    const float* tail_src = (const float*)d_in[2];
    const float* W_e      = (const float*)d_in[3];
    const float* b_e      = (const float*)d_in[4];
    const float* W_r      = (const float*)d_in[5];
    const float* b_r      = (const float*)d_in[6];
    const float* core     = (const float*)d_in[7];

    hipMemsetAsync(d_ws, 0, 4, stream);  // zero the arrival counter
    tucker_kernel<<<NGRID, 256, 0, stream>>>(
        core, head_src, rel_src, tail_src, W_e, b_e, W_r, b_r,
        (float*)d_ws, (float*)d_out);
}

// Round 4
// 81.066 us; speedup vs baseline: 1.3322x; 1.3322x over previous
//
#include <hip/hip_runtime.h>

#define HDIM 768
#define EDIM 128
#define BDIM 64

#define NCORE_BLOCKS 256   // 2 blocks per slab i; 8 independent float4/thread
#define NPROJ_BLOCKS 768   // 3072 waves: 3 matrices x 64 b x 16 i-chunks

// ws layout (floats): [64..320)    partials[256]  (2 half-sums per slab i)
//                     [1024..25600) P[3][64][128]
#define WS_PARTIALS 64
#define WS_P 1024

__global__ __launch_bounds__(256) void fused_kernel(
    const float* __restrict__ core,
    const float* __restrict__ head_src, const float* __restrict__ rel_src,
    const float* __restrict__ tail_src,
    const float* __restrict__ W_e, const float* __restrict__ b_e,
    const float* __restrict__ W_r, const float* __restrict__ b_r,
    float* __restrict__ ws) {
    float* partials = ws + WS_PARTIALS;
    float* P        = ws + WS_P;

    const int blk = blockIdx.x;
    const int t = threadIdx.x;
    const int wave = t >> 6, lane = t & 63;

    if (blk < NCORE_BLOCKS) {
        // core slab half-sum: slab i = blk>>1, half = blk&1 (8192 floats).
        // 8 independent float4 loads per thread -> 128 B in flight (MLP).
        const int i = blk >> 1, h = blk & 1;
        const float4* p = (const float4*)(core + (size_t)i * 16384 + (size_t)h * 8192);
        float4 v0 = p[t], v1 = p[t + 256], v2 = p[t + 512], v3 = p[t + 768];
        float4 v4 = p[t + 1024], v5 = p[t + 1280], v6 = p[t + 1536], v7 = p[t + 1792];
        float s = ((v0.x + v0.y) + (v0.z + v0.w)) + ((v1.x + v1.y) + (v1.z + v1.w))
                + ((v2.x + v2.y) + (v2.z + v2.w)) + ((v3.x + v3.y) + (v3.z + v3.w))
                + ((v4.x + v4.y) + (v4.z + v4.w)) + ((v5.x + v5.y) + (v5.z + v5.w))
                + ((v6.x + v6.y) + (v6.z + v6.w)) + ((v7.x + v7.y) + (v7.z + v7.w));
        for (int off = 32; off; off >>= 1) s += __shfl_down(s, off, 64);
        __shared__ float wpart[4];
        if (lane == 0) wpart[wave] = s;
        __syncthreads();
        if (t == 0) partials[blk] = (wpart[0] + wpart[1]) + (wpart[2] + wpart[3]);
    } else {
        // projections: wave task = (m, b, i-chunk of 8 output channels).
        // Coalesced float4 loads; src row held in regs; 6-step shuffle reduce.
        const int wt  = (blk - NCORE_BLOCKS) * 4 + wave;  // 0..3071
        const int ich = wt & 15;
        const int mb  = wt >> 4;                          // 0..191
        const int m   = mb >> 6;                          // 0=head 1=rel 2=tail
        const int b   = mb & 63;

        const float* src  = (m == 0) ? head_src : (m == 1) ? rel_src : tail_src;
        const float* W    = (m == 1) ? W_r : W_e;
        const float* bias = (m == 1) ? b_r : b_e;

        const float4* s4 = (const float4*)(src + b * HDIM);
        const float4 x0 = s4[lane], x1 = s4[lane + 64], x2 = s4[lane + 128];

        const int i0 = ich * 8;
#pragma unroll
        for (int u = 0; u < 8; ++u) {
            const int i = i0 + u;
            const float4* w4 = (const float4*)(W + i * HDIM);
            const float4 w0 = w4[lane], w1 = w4[lane + 64], w2 = w4[lane + 128];
            float d = w0.x * x0.x + w0.y * x0.y + w0.z * x0.z + w0.w * x0.w
                    + w1.x * x1.x + w1.y * x1.y + w1.z * x1.z + w1.w * x1.w
                    + w2.x * x2.x + w2.y * x2.y + w2.z * x2.z + w2.w * x2.w;
            for (int off = 32; off; off >>= 1) d += __shfl_down(d, off, 64);
            if (lane == 0) P[(m * BDIM + b) * EDIM + i] = d + bias[i];
        }
    }
}

// Final: one block per b. thread i: val = S[i]*h*r*t; block-reduce -> out[b].
__global__ __launch_bounds__(128) void final_kernel(
    const float* __restrict__ ws, float* __restrict__ out) {
    const float* partials = ws + WS_PARTIALS;
    const float* P        = ws + WS_P;
    const int b = blockIdx.x;
    const int i = threadIdx.x;  // 0..127

    const float S = partials[2 * i] + partials[2 * i + 1];
    const float h  = P[(0 * BDIM + b) * EDIM + i];
    const float r  = P[(1 * BDIM + b) * EDIM + i];
    const float tt = P[(2 * BDIM + b) * EDIM + i];
    float val = S * h * r * tt;

    for (int off = 32; off; off >>= 1) val += __shfl_down(val, off, 64);
    __shared__ float wsum[2];
    if ((i & 63) == 0) wsum[i >> 6] = val;
    __syncthreads();
    if (i == 0) out[b] = -(wsum[0] + wsum[1]);
}

extern "C" void kernel_launch(void* const* d_in, const int* in_sizes, int n_in,
                              void* d_out, int out_size, void* d_ws, size_t ws_size,
                              hipStream_t stream) {
    const float* head_src = (const float*)d_in[0];
    const float* rel_src  = (const float*)d_in[1];
    const float* tail_src = (const float*)d_in[2];
    const float* W_e      = (const float*)d_in[3];
    const float* b_e      = (const float*)d_in[4];
    const float* W_r      = (const float*)d_in[5];
    const float* b_r      = (const float*)d_in[6];
    const float* core     = (const float*)d_in[7];

    fused_kernel<<<NCORE_BLOCKS + NPROJ_BLOCKS, 256, 0, stream>>>(
        core, head_src, rel_src, tail_src, W_e, b_e, W_r, b_r, (float*)d_ws);
    final_kernel<<<BDIM, 128, 0, stream>>>((const float*)d_ws, (float*)d_out);
}